// Round 6
// baseline (221.482 us; speedup 1.0000x reference)
//
#include <hip/hip_runtime.h>

#define NN 100000
#define NE 1600000
#define DD 64
#define NB   391     // 256-row buckets: b = row >> 8 (99999>>8 = 390)
#define NBK1 391     // K1 blocks, 4096 edges each (391*4096 >= NE)
#define BCAP 4608    // bucket slab cap (mean 4096, +8 sigma)
#define SCAP 6656    // K2 LDS sorted cap (hard max 4608 + 256*7 = 6400)
#define GCAP 2400000 // gsorted record cap (expected ~1.95M incl. padding)
#define NK3  1563    // K3 blocks, 64 nodes each

__device__ __forceinline__ unsigned short f2bfu(float f) {
    union { float f; unsigned u; } c; c.f = f;
    unsigned lsb = (c.u >> 16) & 1u;
    c.u += 0x7FFFu + lsb;
    return (unsigned short)(c.u >> 16);
}

typedef short v8s __attribute__((ext_vector_type(8)));
typedef float v4f __attribute__((ext_vector_type(4)));

// ===== K0: init: zero cursors, pre-convert W0/W1 -> bf16 =====
__global__ __launch_bounds__(256) void init_kernel(
    const float* __restrict__ W0, const float* __restrict__ W1,
    int* __restrict__ gbcur, int* __restrict__ gtail,
    unsigned short* __restrict__ wb0, unsigned short* __restrict__ wb1)
{
    int i = blockIdx.x * 256 + threadIdx.x;     // grid 16*256 = 4096 threads
    if (i < NB) gbcur[i] = 0;
    if (i == 0) *gtail = 0;
    if (i < DD * DD) { wb0[i] = f2bfu(W0[i]); wb1[i] = f2bfu(W1[i]); }
}

// ===== K1: coarse bucket scatter (391 x 256-row buckets) =====
// Record: (col | (row&255) << 17, val). Kept structurally unchanged this
// round for attribution: if scattered 8B stores are the hidden ~60us cost,
// K1 will now surface above the slimmed K3 in top-5.
__global__ __launch_bounds__(512) void bucket_scatter_kernel(
    const int* __restrict__ row, const int* __restrict__ col,
    const float* __restrict__ val, int* __restrict__ gbcur,
    int2* __restrict__ bslab)
{
    __shared__ int hist[NB];                 // 1564 B
    int b = blockIdx.x, t = threadIdx.x;
    if (t < NB) hist[t] = 0;
    __syncthreads();

    int4 r[2], c[2]; float4 v[2]; bool ok[2];
#pragma unroll
    for (int h = 0; h < 2; ++h) {
        int e = b * 4096 + h * 2048 + t * 4;
        ok[h] = (e + 3 < NE);
        if (ok[h]) {
            r[h] = *(const int4*)(row + e);
            c[h] = *(const int4*)(col + e);
            v[h] = *(const float4*)(val + e);
            atomicAdd(&hist[r[h].x >> 8], 1);
            atomicAdd(&hist[r[h].y >> 8], 1);
            atomicAdd(&hist[r[h].z >> 8], 1);
            atomicAdd(&hist[r[h].w >> 8], 1);
        }
    }
    __syncthreads();
    if (t < NB) {
        int cnt = hist[t];
        hist[t] = cnt ? atomicAdd(&gbcur[t], cnt) : 0;
    }
    __syncthreads();
#pragma unroll
    for (int h = 0; h < 2; ++h) {
        if (ok[h]) {
            int b0_ = r[h].x >> 8, b1_ = r[h].y >> 8;
            int b2_ = r[h].z >> 8, b3_ = r[h].w >> 8;
            int q0 = atomicAdd(&hist[b0_], 1);
            int q1 = atomicAdd(&hist[b1_], 1);
            int q2 = atomicAdd(&hist[b2_], 1);
            int q3 = atomicAdd(&hist[b3_], 1);
            if (q0 < BCAP) bslab[(size_t)b0_ * BCAP + q0] =
                make_int2(c[h].x | ((r[h].x & 255) << 17), __float_as_int(v[h].x));
            if (q1 < BCAP) bslab[(size_t)b1_ * BCAP + q1] =
                make_int2(c[h].y | ((r[h].y & 255) << 17), __float_as_int(v[h].y));
            if (q2 < BCAP) bslab[(size_t)b2_ * BCAP + q2] =
                make_int2(c[h].z | ((r[h].z & 255) << 17), __float_as_int(v[h].z));
            if (q3 < BCAP) bslab[(size_t)b3_ * BCAP + q3] =
                make_int2(c[h].w | ((r[h].w & 255) << 17), __float_as_int(v[h].w));
        }
    }
}

// ===== K2: per-bucket FULL row-sort -> 8-padded runs + meta (round-0 format) =====
// One 512-thread block per bucket. Register-stage records, LDS counting sort
// by the 256 local rows, reserve global space with ONE atomic, write the
// sorted stream out LINEARLY (fully coalesced). meta[n] = (start8 << 5) | cc.
__global__ __launch_bounds__(512) void row_sort_kernel(
    const int* __restrict__ gbcur, const int2* __restrict__ bslab,
    int* __restrict__ gtail, int2* __restrict__ gsorted,
    int* __restrict__ meta)
{
    __shared__ int2 sorted[SCAP];            // 53248 B
    __shared__ int cnt[256];
    __shared__ int pscan[256];
    __shared__ int rcur[256];
    __shared__ int pstart[257];
    __shared__ int sh_base8;                 // total ~57.5 KB -> 2 blocks/CU

    int b = blockIdx.x, t = threadIdx.x;
    int nb = min(gbcur[b], BCAP);
    const int2* bp = bslab + (size_t)b * BCAP;

    int2 rec[9]; int rl[9]; int nr = 0;
    if (t < 256) cnt[t] = 0;
    __syncthreads();
#pragma unroll
    for (int k = 0; k < 9; ++k) {
        int i = t + k * 512;
        if (i < nb) {
            rec[nr] = bp[i];
            rl[nr] = (rec[nr].x >> 17) & 255;
            atomicAdd(&cnt[rl[nr]], 1);
            ++nr;
        }
    }
    __syncthreads();
    if (t < 256) pscan[t] = (cnt[t] + 7) & ~7;   // pad rows to multiple of 8
    __syncthreads();
    for (int off = 1; off < 256; off <<= 1) {
        int u = 0;
        if (t < 256 && t >= off) u = pscan[t - off];
        __syncthreads();
        if (t < 256) pscan[t] += u;
        __syncthreads();
    }
    if (t < 256) pstart[t + 1] = pscan[t];
    if (t == 0) {
        pstart[0] = 0;
        sh_base8 = atomicAdd(gtail, pscan[255] >> 3);   // one reserve per block
    }
    __syncthreads();
    int base8 = sh_base8;
    if (t < 256) {
        rcur[t] = pstart[t];
        int s = pstart[t] + cnt[t], e = pstart[t + 1];
        for (int j = s; j < e; ++j) sorted[j] = make_int2(0, 0);  // zero pads
        int n = b * 256 + t;                  // n may exceed NN-1 (harmless)
        int cc = min((e - pstart[t]) >> 3, 16);
        int s8 = base8 + (pstart[t] >> 3);
        meta[n] = (s8 << 5) | cc;
    }
    __syncthreads();
#pragma unroll
    for (int k = 0; k < 9; ++k) {
        if (k < nr) {
            int pos = atomicAdd(&rcur[rl[k]], 1);
            if (pos < SCAP) sorted[pos] = make_int2(rec[k].x & 0x1FFFF, rec[k].y);
        }
    }
    __syncthreads();
    int tp = pscan[255];
    int gb = base8 * 8;
    for (int i = t; i < tp; i += 512) {
        int gi = gb + i;
        if (gi < GCAP) gsorted[gi] = sorted[i];   // linear, fully coalesced
    }
}

// ===== K3: sort-free pull-SpMM + MFMA transform + rownorm =====
// No ebuf, no scan, NO BARRIERS. Edge records read directly from global:
// per wave-instruction the 64 lanes touch 4 consecutive 8B records (one 32B
// transaction + broadcast); consecutive nodes' runs are contiguous in memory.
__global__ __launch_bounds__(256, 4) void pull_mfma_kernel(
    const float* __restrict__ x, const int* __restrict__ meta,
    const int2* __restrict__ gsorted,
    const unsigned short* __restrict__ wb0, const unsigned short* __restrict__ wb1,
    const float* __restrict__ b0, const float* __restrict__ s0, const float* __restrict__ o0,
    const float* __restrict__ b1, const float* __restrict__ s1, const float* __restrict__ o1,
    float* __restrict__ out)
{
    __shared__ unsigned aggt[4][16][36];     // 9216 B only

    int t = threadIdx.x, lane = t & 63, wv = t >> 6;
    int sub = lane & 15, q = lane >> 4;
    int nb0 = blockIdx.x * 64 + wv * 16;
    if (nb0 >= NN) return;                   // whole-wave tails; no barriers below

    // ---- phase 1: gather-aggregate straight from the sorted stream ----
    for (int rr = 0; rr < 16; ++rr) {
        int mt = meta[nb0 + rr];
        int cc = mt & 31;
        const int2* rp = gsorted + ((size_t)(mt >> 5) << 3);
        float4 acc = make_float4(0.f, 0.f, 0.f, 0.f);
        int ch = 0;
        for (; ch + 2 <= cc; ch += 2) {
            int2 r0 = rp[ch * 8 + q];
            int2 r1 = rp[ch * 8 + 4 + q];
            int2 r2 = rp[ch * 8 + 8 + q];
            int2 r3 = rp[ch * 8 + 12 + q];
            float4 f0 = *(const float4*)(x + (size_t)r0.x * DD + sub * 4);
            float4 f1 = *(const float4*)(x + (size_t)r1.x * DD + sub * 4);
            float4 f2 = *(const float4*)(x + (size_t)r2.x * DD + sub * 4);
            float4 f3 = *(const float4*)(x + (size_t)r3.x * DD + sub * 4);
            float v0 = __int_as_float(r0.y), v1 = __int_as_float(r1.y);
            float v2 = __int_as_float(r2.y), v3 = __int_as_float(r3.y);
            acc.x = fmaf(v0, f0.x, acc.x); acc.y = fmaf(v0, f0.y, acc.y);
            acc.z = fmaf(v0, f0.z, acc.z); acc.w = fmaf(v0, f0.w, acc.w);
            acc.x = fmaf(v1, f1.x, acc.x); acc.y = fmaf(v1, f1.y, acc.y);
            acc.z = fmaf(v1, f1.z, acc.z); acc.w = fmaf(v1, f1.w, acc.w);
            acc.x = fmaf(v2, f2.x, acc.x); acc.y = fmaf(v2, f2.y, acc.y);
            acc.z = fmaf(v2, f2.z, acc.z); acc.w = fmaf(v2, f2.w, acc.w);
            acc.x = fmaf(v3, f3.x, acc.x); acc.y = fmaf(v3, f3.y, acc.y);
            acc.z = fmaf(v3, f3.z, acc.z); acc.w = fmaf(v3, f3.w, acc.w);
        }
        if (ch < cc) {
            int2 r0 = rp[ch * 8 + q];
            int2 r1 = rp[ch * 8 + 4 + q];
            float4 f0 = *(const float4*)(x + (size_t)r0.x * DD + sub * 4);
            float4 f1 = *(const float4*)(x + (size_t)r1.x * DD + sub * 4);
            float v0 = __int_as_float(r0.y), v1 = __int_as_float(r1.y);
            acc.x = fmaf(v0, f0.x, acc.x); acc.y = fmaf(v0, f0.y, acc.y);
            acc.z = fmaf(v0, f0.z, acc.z); acc.w = fmaf(v0, f0.w, acc.w);
            acc.x = fmaf(v1, f1.x, acc.x); acc.y = fmaf(v1, f1.y, acc.y);
            acc.z = fmaf(v1, f1.z, acc.z); acc.w = fmaf(v1, f1.w, acc.w);
        }
        acc.x += __shfl_xor(acc.x, 16, 64); acc.y += __shfl_xor(acc.y, 16, 64);
        acc.z += __shfl_xor(acc.z, 16, 64); acc.w += __shfl_xor(acc.w, 16, 64);
        acc.x += __shfl_xor(acc.x, 32, 64); acc.y += __shfl_xor(acc.y, 32, 64);
        acc.z += __shfl_xor(acc.z, 32, 64); acc.w += __shfl_xor(acc.w, 32, 64);
        if (q == 0) {
            uint2 pk;
            pk.x = (unsigned)f2bfu(acc.x) | ((unsigned)f2bfu(acc.y) << 16);
            pk.y = (unsigned)f2bfu(acc.z) | ((unsigned)f2bfu(acc.w) << 16);
            *(uint2*)&aggt[wv][rr][sub * 2] = pk;
        }
    }
    // per-wave tile written by this wave only -> DS pipe is in-order per wave

    // ---- phase 2: two-hop MFMA transform + rownorm for this wave's 16 nodes ----
    v8s ax[2], aa[2];
#pragma unroll
    for (int ks = 0; ks < 2; ++ks) {
        const float* px = x + (size_t)(nb0 + sub) * DD + ks * 32 + q * 8;
        float4 a0 = *(const float4*)px, a1 = *(const float4*)(px + 4);
        v8s w;
        w[0] = (short)f2bfu(a0.x); w[1] = (short)f2bfu(a0.y);
        w[2] = (short)f2bfu(a0.z); w[3] = (short)f2bfu(a0.w);
        w[4] = (short)f2bfu(a1.x); w[5] = (short)f2bfu(a1.y);
        w[6] = (short)f2bfu(a1.z); w[7] = (short)f2bfu(a1.w);
        ax[ks] = w;
        aa[ks] = *(const v8s*)&aggt[wv][sub][ks * 16 + q * 4];
    }

    float h0v[4][4], h1v[4][4];
    float sr0[4] = {0,0,0,0}, sq0[4] = {0,0,0,0};
    float sr1[4] = {0,0,0,0}, sq1[4] = {0,0,0,0};
#pragma unroll
    for (int dt = 0; dt < 4; ++dt) {
        int nidx = dt * 16 + sub;
        float bi0 = b0[nidx], bi1 = b1[nidx];
        v8s w00 = *(const v8s*)(wb0 + nidx * 64 + q * 8);
        v8s w01 = *(const v8s*)(wb0 + nidx * 64 + 32 + q * 8);
        v8s w10 = *(const v8s*)(wb1 + nidx * 64 + q * 8);
        v8s w11 = *(const v8s*)(wb1 + nidx * 64 + 32 + q * 8);
        v4f c0 = (v4f){bi0, bi0, bi0, bi0};
        v4f c1 = (v4f){bi1, bi1, bi1, bi1};
        c0 = __builtin_amdgcn_mfma_f32_16x16x32_bf16(ax[0], w00, c0, 0, 0, 0);
        c0 = __builtin_amdgcn_mfma_f32_16x16x32_bf16(ax[1], w01, c0, 0, 0, 0);
        c1 = __builtin_amdgcn_mfma_f32_16x16x32_bf16(aa[0], w10, c1, 0, 0, 0);
        c1 = __builtin_amdgcn_mfma_f32_16x16x32_bf16(aa[1], w11, c1, 0, 0, 0);
#pragma unroll
        for (int r = 0; r < 4; ++r) {
            float h = fmaxf(c0[r], 0.f); h0v[dt][r] = h; sr0[r] += h; sq0[r] += h * h;
            float g = fmaxf(c1[r], 0.f); h1v[dt][r] = g; sr1[r] += g; sq1[r] += g * g;
        }
    }
#pragma unroll
    for (int off = 1; off < 16; off <<= 1) {
#pragma unroll
        for (int r = 0; r < 4; ++r) {
            sr0[r] += __shfl_xor(sr0[r], off, 64);
            sq0[r] += __shfl_xor(sq0[r], off, 64);
            sr1[r] += __shfl_xor(sr1[r], off, 64);
            sq1[r] += __shfl_xor(sq1[r], off, 64);
        }
    }

    float scl0[4], scl1[4], ofs0[4], ofs1[4];
#pragma unroll
    for (int dt = 0; dt < 4; ++dt) {
        int nidx = dt * 16 + sub;
        scl0[dt] = s0[nidx]; scl1[dt] = s1[nidx];
        ofs0[dt] = o0[nidx]; ofs1[dt] = o1[nidx];
    }

    const float inv = 1.0f / 64.0f;
#pragma unroll
    for (int r = 0; r < 4; ++r) {
        float m0 = sr0[r] * inv;
        float v0 = fmaxf(sq0[r] * inv - m0 * m0, 0.f) + 1e-9f;
        float m1 = sr1[r] * inv;
        float v1 = fmaxf(sq1[r] * inv - m1 * m1, 0.f) + 1e-9f;
        float rs0 = rsqrtf(v0), rs1 = rsqrtf(v1);
        int node = nb0 + q * 4 + r;
#pragma unroll
        for (int dt = 0; dt < 4; ++dt) {
            float rv = (h0v[dt][r] - m0) * scl0[dt] * rs0 + ofs0[dt]
                     + (h1v[dt][r] - m1) * scl1[dt] * rs1 + ofs1[dt];
            out[(size_t)node * DD + dt * 16 + sub] = rv;   // 64B-coalesced per quad
        }
    }
}

extern "C" void kernel_launch(void* const* d_in, const int* in_sizes, int n_in,
                              void* d_out, int out_size, void* d_ws, size_t ws_size,
                              hipStream_t stream) {
    const float* x  = (const float*)d_in[0];
    const float* ev = (const float*)d_in[1];
    const float* W0 = (const float*)d_in[2];
    const float* b0 = (const float*)d_in[3];
    const float* s0 = (const float*)d_in[4];
    const float* o0 = (const float*)d_in[5];
    const float* W1 = (const float*)d_in[6];
    const float* b1 = (const float*)d_in[7];
    const float* s1 = (const float*)d_in[8];
    const float* o1 = (const float*)d_in[9];
    const int* row = (const int*)d_in[10];
    const int* col = (const int*)d_in[11];

    // ws byte layout (64B-aligned):
    //   gbcur:   0          (1564 B, pad 1600)
    //   gtail:   1600       (4 B, pad to 1664)
    //   wb0:     1664       (8192 B)
    //   wb1:     9856       (8192 B, end 18048, pad 18176)
    //   meta:    18176      (391*256*4 = 400384 B, end 418560, pad 418816)
    //   bslab:   418816     (391*4608*8 = 14,413,824 B, end 14,832,640)
    //   gsorted: 14,832,640 ((2,400,000+128)*8 = 19,201,024 B, end ~34.0 MB)
    char* wsb = (char*)d_ws;
    int*  gbcur = (int*)wsb;
    int*  gtail = (int*)(wsb + 1600);
    unsigned short* wb0 = (unsigned short*)(wsb + 1664);
    unsigned short* wb1 = (unsigned short*)(wsb + 9856);
    int*  meta  = (int*)(wsb + 18176);
    int2* bslab = (int2*)(wsb + 418816);
    int2* gsorted = (int2*)(wsb + 14832640);

    init_kernel<<<16, 256, 0, stream>>>(W0, W1, gbcur, gtail, wb0, wb1);
    bucket_scatter_kernel<<<NBK1, 512, 0, stream>>>(row, col, ev, gbcur, bslab);
    row_sort_kernel<<<NB, 512, 0, stream>>>(gbcur, bslab, gtail, gsorted, meta);
    pull_mfma_kernel<<<NK3, 256, 0, stream>>>(
        x, meta, gsorted, wb0, wb1, b0, s0, o0, b1, s1, o1, (float*)d_out);
}

// Round 7
// 218.252 us; speedup vs baseline: 1.0148x; 1.0148x over previous
//
#include <hip/hip_runtime.h>

#define NN 100000
#define NE 1600000
#define DD 64
#define NB   391     // 256-row buckets: b = row >> 8 (99999>>8 = 390)
#define NBK1 391     // K1 blocks, 4096 edges each (391*4096 >= NE)
#define BCAP 4608    // bucket slab cap (mean 4096, +8 sigma)
#define SCAP 3456    // K2' LDS sorted cap PER HALF (padded mean ~2494, ~18 sigma)

__device__ __forceinline__ unsigned short f2bfu(float f) {
    union { float f; unsigned u; } c; c.f = f;
    unsigned lsb = (c.u >> 16) & 1u;
    c.u += 0x7FFFu + lsb;
    return (unsigned short)(c.u >> 16);
}

typedef short v8s __attribute__((ext_vector_type(8)));
typedef float v4f __attribute__((ext_vector_type(4)));

// ===== K0: init: zero bucket cursors, pre-convert W0/W1 -> bf16 =====
__global__ __launch_bounds__(256) void init_kernel(
    const float* __restrict__ W0, const float* __restrict__ W1,
    int* __restrict__ gbcur,
    unsigned short* __restrict__ wb0, unsigned short* __restrict__ wb1)
{
    int i = blockIdx.x * 256 + threadIdx.x;     // grid 16*256 = 4096 threads
    if (i < NB) gbcur[i] = 0;
    if (i < DD * DD) { wb0[i] = f2bfu(W0[i]); wb1[i] = f2bfu(W1[i]); }
}

// ===== K1: coarse bucket scatter (391 x 256-row buckets) — UNCHANGED from r6 =====
// Record: (col | (row&255) << 17, val).
__global__ __launch_bounds__(512) void bucket_scatter_kernel(
    const int* __restrict__ row, const int* __restrict__ col,
    const float* __restrict__ val, int* __restrict__ gbcur,
    int2* __restrict__ bslab)
{
    __shared__ int hist[NB];                 // 1564 B
    int b = blockIdx.x, t = threadIdx.x;
    if (t < NB) hist[t] = 0;
    __syncthreads();

    int4 r[2], c[2]; float4 v[2]; bool ok[2];
#pragma unroll
    for (int h = 0; h < 2; ++h) {
        int e = b * 4096 + h * 2048 + t * 4;
        ok[h] = (e + 3 < NE);
        if (ok[h]) {
            r[h] = *(const int4*)(row + e);
            c[h] = *(const int4*)(col + e);
            v[h] = *(const float4*)(val + e);
            atomicAdd(&hist[r[h].x >> 8], 1);
            atomicAdd(&hist[r[h].y >> 8], 1);
            atomicAdd(&hist[r[h].z >> 8], 1);
            atomicAdd(&hist[r[h].w >> 8], 1);
        }
    }
    __syncthreads();
    if (t < NB) {
        int cnt = hist[t];
        hist[t] = cnt ? atomicAdd(&gbcur[t], cnt) : 0;
    }
    __syncthreads();
#pragma unroll
    for (int h = 0; h < 2; ++h) {
        if (ok[h]) {
            int b0_ = r[h].x >> 8, b1_ = r[h].y >> 8;
            int b2_ = r[h].z >> 8, b3_ = r[h].w >> 8;
            int q0 = atomicAdd(&hist[b0_], 1);
            int q1 = atomicAdd(&hist[b1_], 1);
            int q2 = atomicAdd(&hist[b2_], 1);
            int q3 = atomicAdd(&hist[b3_], 1);
            if (q0 < BCAP) bslab[(size_t)b0_ * BCAP + q0] =
                make_int2(c[h].x | ((r[h].x & 255) << 17), __float_as_int(v[h].x));
            if (q1 < BCAP) bslab[(size_t)b1_ * BCAP + q1] =
                make_int2(c[h].y | ((r[h].y & 255) << 17), __float_as_int(v[h].y));
            if (q2 < BCAP) bslab[(size_t)b2_ * BCAP + q2] =
                make_int2(c[h].z | ((r[h].z & 255) << 17), __float_as_int(v[h].z));
            if (q3 < BCAP) bslab[(size_t)b3_ * BCAP + q3] =
                make_int2(c[h].w | ((r[h].w & 255) << 17), __float_as_int(v[h].w));
        }
    }
}

// ===== K2': per-bucket sort + pull-SpMM + MFMA + rownorm, all in one kernel =====
// One 512-thread (8-wave) block per 256-row bucket; two 128-row half-passes.
// Sorted records never leave LDS. 48.6 KB LDS -> 3 blocks/CU (75% occupancy).
__global__ __launch_bounds__(512, 6) void sort_pull_mfma_kernel(
    const float* __restrict__ x, const int* __restrict__ gbcur,
    const int2* __restrict__ bslab,
    const unsigned short* __restrict__ wb0, const unsigned short* __restrict__ wb1,
    const float* __restrict__ b0, const float* __restrict__ s0, const float* __restrict__ o0,
    const float* __restrict__ b1, const float* __restrict__ s1, const float* __restrict__ o1,
    float* __restrict__ out)
{
    __shared__ int2 sorted[SCAP];            // 27648 B (reused per half)
    __shared__ unsigned aggt[8][16][36];     // 18432 B (16x64 bf16 per wave)
    __shared__ int cnt[256];                 // 1024 B
    __shared__ int pscan[128];               // 512 B
    __shared__ int rcur[128];                // 512 B
    __shared__ int pstart[129];              // 516 B   -- total 48644 B

    int bkt = blockIdx.x, t = threadIdx.x;
    int nb = min(gbcur[bkt], BCAP);
    const int2* bp = bslab + (size_t)bkt * BCAP;

    int lane = t & 63, wv = t >> 6;
    int sub = lane & 15, q = lane >> 4;

    // ---- count all 256 row-bins (bslab is L2-resident: 32 KB/bucket) ----
    if (t < 256) cnt[t] = 0;
    __syncthreads();
    for (int i = t; i < nb; i += 512)
        atomicAdd(&cnt[(bp[i].x >> 17) & 255], 1);

    for (int half = 0; half < 2; ++half) {
        __syncthreads();                     // prev phase done (count / prev gather)
        // ---- 8-padded exclusive scan over this half's 128 bins ----
        if (t < 128) pscan[t] = (cnt[half * 128 + t] + 7) & ~7;
        __syncthreads();
        for (int off = 1; off < 128; off <<= 1) {
            int u = 0;
            if (t < 128 && t >= off) u = pscan[t - off];
            __syncthreads();
            if (t < 128) pscan[t] += u;
            __syncthreads();
        }
        if (t < 128) pstart[t + 1] = min(pscan[t], SCAP);
        if (t == 0) pstart[0] = 0;
        __syncthreads();
        if (t < 128) {
            rcur[t] = pstart[t];
            int s = min(pstart[t] + cnt[half * 128 + t], SCAP);
            int e = pstart[t + 1];
            for (int j = s; j < e; ++j) sorted[j] = make_int2(0, 0);  // zero pads
        }
        __syncthreads();
        // ---- counting-scatter this half's records into 8-padded runs ----
        for (int i = t; i < nb; i += 512) {
            int2 rc = bp[i];
            int rl = (rc.x >> 17) & 255;
            if ((rl >> 7) == half) {
                int pos = atomicAdd(&rcur[rl & 127], 1);
                if (pos < SCAP) sorted[pos] = make_int2(rc.x & 0x1FFFF, rc.y);
            }
        }
        __syncthreads();

        // ---- gather-aggregate: each wave owns 16 rows of this half ----
        int nb0 = bkt * 256 + half * 128 + wv * 16;
        for (int rr = 0; rr < 16; ++rr) {
            int lr = wv * 16 + rr;
            int start = pstart[lr];
            int cc = min((pstart[lr + 1] - start) >> 3, 16);
            float4 acc = make_float4(0.f, 0.f, 0.f, 0.f);
            int ch = 0;
            for (; ch + 2 <= cc; ch += 2) {
                int2 r0 = sorted[start + ch * 8 + q];
                int2 r1 = sorted[start + ch * 8 + 4 + q];
                int2 r2 = sorted[start + ch * 8 + 8 + q];
                int2 r3 = sorted[start + ch * 8 + 12 + q];
                float4 f0 = *(const float4*)(x + (size_t)r0.x * DD + sub * 4);
                float4 f1 = *(const float4*)(x + (size_t)r1.x * DD + sub * 4);
                float4 f2 = *(const float4*)(x + (size_t)r2.x * DD + sub * 4);
                float4 f3 = *(const float4*)(x + (size_t)r3.x * DD + sub * 4);
                float v0 = __int_as_float(r0.y), v1 = __int_as_float(r1.y);
                float v2 = __int_as_float(r2.y), v3 = __int_as_float(r3.y);
                acc.x = fmaf(v0, f0.x, acc.x); acc.y = fmaf(v0, f0.y, acc.y);
                acc.z = fmaf(v0, f0.z, acc.z); acc.w = fmaf(v0, f0.w, acc.w);
                acc.x = fmaf(v1, f1.x, acc.x); acc.y = fmaf(v1, f1.y, acc.y);
                acc.z = fmaf(v1, f1.z, acc.z); acc.w = fmaf(v1, f1.w, acc.w);
                acc.x = fmaf(v2, f2.x, acc.x); acc.y = fmaf(v2, f2.y, acc.y);
                acc.z = fmaf(v2, f2.z, acc.z); acc.w = fmaf(v2, f2.w, acc.w);
                acc.x = fmaf(v3, f3.x, acc.x); acc.y = fmaf(v3, f3.y, acc.y);
                acc.z = fmaf(v3, f3.z, acc.z); acc.w = fmaf(v3, f3.w, acc.w);
            }
            if (ch < cc) {
                int2 r0 = sorted[start + ch * 8 + q];
                int2 r1 = sorted[start + ch * 8 + 4 + q];
                float4 f0 = *(const float4*)(x + (size_t)r0.x * DD + sub * 4);
                float4 f1 = *(const float4*)(x + (size_t)r1.x * DD + sub * 4);
                float v0 = __int_as_float(r0.y), v1 = __int_as_float(r1.y);
                acc.x = fmaf(v0, f0.x, acc.x); acc.y = fmaf(v0, f0.y, acc.y);
                acc.z = fmaf(v0, f0.z, acc.z); acc.w = fmaf(v0, f0.w, acc.w);
                acc.x = fmaf(v1, f1.x, acc.x); acc.y = fmaf(v1, f1.y, acc.y);
                acc.z = fmaf(v1, f1.z, acc.z); acc.w = fmaf(v1, f1.w, acc.w);
            }
            acc.x += __shfl_xor(acc.x, 16, 64); acc.y += __shfl_xor(acc.y, 16, 64);
            acc.z += __shfl_xor(acc.z, 16, 64); acc.w += __shfl_xor(acc.w, 16, 64);
            acc.x += __shfl_xor(acc.x, 32, 64); acc.y += __shfl_xor(acc.y, 32, 64);
            acc.z += __shfl_xor(acc.z, 32, 64); acc.w += __shfl_xor(acc.w, 32, 64);
            if (q == 0) {
                uint2 pk;
                pk.x = (unsigned)f2bfu(acc.x) | ((unsigned)f2bfu(acc.y) << 16);
                pk.y = (unsigned)f2bfu(acc.z) | ((unsigned)f2bfu(acc.w) << 16);
                *(uint2*)&aggt[wv][rr][sub * 2] = pk;
            }
        }
        // per-wave aggt tile: DS pipe in-order per wave -> no barrier before reads

        // ---- two-hop MFMA transform + rownorm (whole-wave validity: NN%16==0) ----
        if (nb0 < NN) {
            v8s ax[2], aa[2];
#pragma unroll
            for (int ks = 0; ks < 2; ++ks) {
                const float* px = x + (size_t)(nb0 + sub) * DD + ks * 32 + q * 8;
                float4 a0 = *(const float4*)px, a1 = *(const float4*)(px + 4);
                v8s w;
                w[0] = (short)f2bfu(a0.x); w[1] = (short)f2bfu(a0.y);
                w[2] = (short)f2bfu(a0.z); w[3] = (short)f2bfu(a0.w);
                w[4] = (short)f2bfu(a1.x); w[5] = (short)f2bfu(a1.y);
                w[6] = (short)f2bfu(a1.z); w[7] = (short)f2bfu(a1.w);
                ax[ks] = w;
                aa[ks] = *(const v8s*)&aggt[wv][sub][ks * 16 + q * 4];
            }

            float h0v[4][4], h1v[4][4];
            float sr0[4] = {0,0,0,0}, sq0[4] = {0,0,0,0};
            float sr1[4] = {0,0,0,0}, sq1[4] = {0,0,0,0};
#pragma unroll
            for (int dt = 0; dt < 4; ++dt) {
                int nidx = dt * 16 + sub;
                float bi0 = b0[nidx], bi1 = b1[nidx];
                v8s w00 = *(const v8s*)(wb0 + nidx * 64 + q * 8);
                v8s w01 = *(const v8s*)(wb0 + nidx * 64 + 32 + q * 8);
                v8s w10 = *(const v8s*)(wb1 + nidx * 64 + q * 8);
                v8s w11 = *(const v8s*)(wb1 + nidx * 64 + 32 + q * 8);
                v4f c0 = (v4f){bi0, bi0, bi0, bi0};
                v4f c1 = (v4f){bi1, bi1, bi1, bi1};
                c0 = __builtin_amdgcn_mfma_f32_16x16x32_bf16(ax[0], w00, c0, 0, 0, 0);
                c0 = __builtin_amdgcn_mfma_f32_16x16x32_bf16(ax[1], w01, c0, 0, 0, 0);
                c1 = __builtin_amdgcn_mfma_f32_16x16x32_bf16(aa[0], w10, c1, 0, 0, 0);
                c1 = __builtin_amdgcn_mfma_f32_16x16x32_bf16(aa[1], w11, c1, 0, 0, 0);
#pragma unroll
                for (int r = 0; r < 4; ++r) {
                    float h = fmaxf(c0[r], 0.f); h0v[dt][r] = h; sr0[r] += h; sq0[r] += h * h;
                    float g = fmaxf(c1[r], 0.f); h1v[dt][r] = g; sr1[r] += g; sq1[r] += g * g;
                }
            }
#pragma unroll
            for (int off = 1; off < 16; off <<= 1) {
#pragma unroll
                for (int r = 0; r < 4; ++r) {
                    sr0[r] += __shfl_xor(sr0[r], off, 64);
                    sq0[r] += __shfl_xor(sq0[r], off, 64);
                    sr1[r] += __shfl_xor(sr1[r], off, 64);
                    sq1[r] += __shfl_xor(sq1[r], off, 64);
                }
            }

            float scl0[4], scl1[4], ofs0[4], ofs1[4];
#pragma unroll
            for (int dt = 0; dt < 4; ++dt) {
                int nidx = dt * 16 + sub;
                scl0[dt] = s0[nidx]; scl1[dt] = s1[nidx];
                ofs0[dt] = o0[nidx]; ofs1[dt] = o1[nidx];
            }

            const float inv = 1.0f / 64.0f;
#pragma unroll
            for (int r = 0; r < 4; ++r) {
                float m0 = sr0[r] * inv;
                float v0 = fmaxf(sq0[r] * inv - m0 * m0, 0.f) + 1e-9f;
                float m1 = sr1[r] * inv;
                float v1 = fmaxf(sq1[r] * inv - m1 * m1, 0.f) + 1e-9f;
                float rs0 = rsqrtf(v0), rs1 = rsqrtf(v1);
                int node = nb0 + q * 4 + r;
#pragma unroll
                for (int dt = 0; dt < 4; ++dt) {
                    float rv = (h0v[dt][r] - m0) * scl0[dt] * rs0 + ofs0[dt]
                             + (h1v[dt][r] - m1) * scl1[dt] * rs1 + ofs1[dt];
                    out[(size_t)node * DD + dt * 16 + sub] = rv;   // 64B-coalesced/quad
                }
            }
        }
    }
}

extern "C" void kernel_launch(void* const* d_in, const int* in_sizes, int n_in,
                              void* d_out, int out_size, void* d_ws, size_t ws_size,
                              hipStream_t stream) {
    const float* x  = (const float*)d_in[0];
    const float* ev = (const float*)d_in[1];
    const float* W0 = (const float*)d_in[2];
    const float* b0 = (const float*)d_in[3];
    const float* s0 = (const float*)d_in[4];
    const float* o0 = (const float*)d_in[5];
    const float* W1 = (const float*)d_in[6];
    const float* b1 = (const float*)d_in[7];
    const float* s1 = (const float*)d_in[8];
    const float* o1 = (const float*)d_in[9];
    const int* row = (const int*)d_in[10];
    const int* col = (const int*)d_in[11];

    // ws byte layout (64B-aligned):
    //   gbcur: 0      (1564 B, pad 1600)
    //   wb0:   1600   (8192 B)
    //   wb1:   9792   (8192 B, end 17984, pad 18048)
    //   bslab: 18048  (391*4608*8 = 14,413,824 B)  -- total ~14.4 MB
    char* wsb = (char*)d_ws;
    int*  gbcur = (int*)wsb;
    unsigned short* wb0 = (unsigned short*)(wsb + 1600);
    unsigned short* wb1 = (unsigned short*)(wsb + 9792);
    int2* bslab = (int2*)(wsb + 18048);

    init_kernel<<<16, 256, 0, stream>>>(W0, W1, gbcur, wb0, wb1);
    bucket_scatter_kernel<<<NBK1, 512, 0, stream>>>(row, col, ev, gbcur, bslab);
    sort_pull_mfma_kernel<<<NB, 512, 0, stream>>>(
        x, gbcur, bslab, wb0, wb1, b0, s0, o0, b1, s1, o1, (float*)d_out);
}

// Round 8
// 213.075 us; speedup vs baseline: 1.0395x; 1.0243x over previous
//
#include <hip/hip_runtime.h>

#define NN 100000
#define NE 1600000
#define DD 64
#define NB   391     // 256-row buckets: b = row >> 8 (99999>>8 = 390)
#define NBK1 391     // K1 blocks, 4096 edges each (391*4096 >= NE)
#define BCAP 4608    // bucket slab cap (mean 4096, +8 sigma)
#define SCAP 6656    // K2 LDS sorted cap (hard max 4608 + 256*7 = 6400)
#define GCAP 2400000 // gsorted record cap (expected ~1.95M incl. padding)
#define NK3  1563    // K3 blocks, 64 nodes each

__device__ __forceinline__ unsigned short f2bfu(float f) {
    union { float f; unsigned u; } c; c.f = f;
    unsigned lsb = (c.u >> 16) & 1u;
    c.u += 0x7FFFu + lsb;
    return (unsigned short)(c.u >> 16);
}

typedef short v8s __attribute__((ext_vector_type(8)));
typedef float v4f __attribute__((ext_vector_type(4)));

// ===== K0: init: zero cursors, pre-convert W0/W1 -> bf16 =====
__global__ __launch_bounds__(256) void init_kernel(
    const float* __restrict__ W0, const float* __restrict__ W1,
    int* __restrict__ gbcur, int* __restrict__ gtail,
    unsigned short* __restrict__ wb0, unsigned short* __restrict__ wb1)
{
    int i = blockIdx.x * 256 + threadIdx.x;     // grid 16*256 = 4096 threads
    if (i < NB) gbcur[i] = 0;
    if (i == 0) *gtail = 0;
    if (i < DD * DD) { wb0[i] = f2bfu(W0[i]); wb1[i] = f2bfu(W1[i]); }
}

// ===== K1: coarse bucket scatter — FROZEN (R6 verbatim) for attribution =====
// Record: (col | (row&255) << 17, val).
__global__ __launch_bounds__(512) void bucket_scatter_kernel(
    const int* __restrict__ row, const int* __restrict__ col,
    const float* __restrict__ val, int* __restrict__ gbcur,
    int2* __restrict__ bslab)
{
    __shared__ int hist[NB];                 // 1564 B
    int b = blockIdx.x, t = threadIdx.x;
    if (t < NB) hist[t] = 0;
    __syncthreads();

    int4 r[2], c[2]; float4 v[2]; bool ok[2];
#pragma unroll
    for (int h = 0; h < 2; ++h) {
        int e = b * 4096 + h * 2048 + t * 4;
        ok[h] = (e + 3 < NE);
        if (ok[h]) {
            r[h] = *(const int4*)(row + e);
            c[h] = *(const int4*)(col + e);
            v[h] = *(const float4*)(val + e);
            atomicAdd(&hist[r[h].x >> 8], 1);
            atomicAdd(&hist[r[h].y >> 8], 1);
            atomicAdd(&hist[r[h].z >> 8], 1);
            atomicAdd(&hist[r[h].w >> 8], 1);
        }
    }
    __syncthreads();
    if (t < NB) {
        int cnt = hist[t];
        hist[t] = cnt ? atomicAdd(&gbcur[t], cnt) : 0;
    }
    __syncthreads();
#pragma unroll
    for (int h = 0; h < 2; ++h) {
        if (ok[h]) {
            int b0_ = r[h].x >> 8, b1_ = r[h].y >> 8;
            int b2_ = r[h].z >> 8, b3_ = r[h].w >> 8;
            int q0 = atomicAdd(&hist[b0_], 1);
            int q1 = atomicAdd(&hist[b1_], 1);
            int q2 = atomicAdd(&hist[b2_], 1);
            int q3 = atomicAdd(&hist[b3_], 1);
            if (q0 < BCAP) bslab[(size_t)b0_ * BCAP + q0] =
                make_int2(c[h].x | ((r[h].x & 255) << 17), __float_as_int(v[h].x));
            if (q1 < BCAP) bslab[(size_t)b1_ * BCAP + q1] =
                make_int2(c[h].y | ((r[h].y & 255) << 17), __float_as_int(v[h].y));
            if (q2 < BCAP) bslab[(size_t)b2_ * BCAP + q2] =
                make_int2(c[h].z | ((r[h].z & 255) << 17), __float_as_int(v[h].z));
            if (q3 < BCAP) bslab[(size_t)b3_ * BCAP + q3] =
                make_int2(c[h].w | ((r[h].w & 255) << 17), __float_as_int(v[h].w));
        }
    }
}

// ===== K2: per-bucket row-sort -> 8-padded runs + meta (R6 verbatim, ~23us) =====
__global__ __launch_bounds__(512) void row_sort_kernel(
    const int* __restrict__ gbcur, const int2* __restrict__ bslab,
    int* __restrict__ gtail, int2* __restrict__ gsorted,
    int* __restrict__ meta)
{
    __shared__ int2 sorted[SCAP];            // 53248 B
    __shared__ int cnt[256];
    __shared__ int pscan[256];
    __shared__ int rcur[256];
    __shared__ int pstart[257];
    __shared__ int sh_base8;                 // total ~57.5 KB -> 2 blocks/CU

    int b = blockIdx.x, t = threadIdx.x;
    int nb = min(gbcur[b], BCAP);
    const int2* bp = bslab + (size_t)b * BCAP;

    int2 rec[9]; int rl[9]; int nr = 0;
    if (t < 256) cnt[t] = 0;
    __syncthreads();
#pragma unroll
    for (int k = 0; k < 9; ++k) {
        int i = t + k * 512;
        if (i < nb) {
            rec[nr] = bp[i];
            rl[nr] = (rec[nr].x >> 17) & 255;
            atomicAdd(&cnt[rl[nr]], 1);
            ++nr;
        }
    }
    __syncthreads();
    if (t < 256) pscan[t] = (cnt[t] + 7) & ~7;   // pad rows to multiple of 8
    __syncthreads();
    for (int off = 1; off < 256; off <<= 1) {
        int u = 0;
        if (t < 256 && t >= off) u = pscan[t - off];
        __syncthreads();
        if (t < 256) pscan[t] += u;
        __syncthreads();
    }
    if (t < 256) pstart[t + 1] = pscan[t];
    if (t == 0) {
        pstart[0] = 0;
        sh_base8 = atomicAdd(gtail, pscan[255] >> 3);   // one reserve per block
    }
    __syncthreads();
    int base8 = sh_base8;
    if (t < 256) {
        rcur[t] = pstart[t];
        int s = pstart[t] + cnt[t], e = pstart[t + 1];
        for (int j = s; j < e; ++j) sorted[j] = make_int2(0, 0);  // zero pads
        int n = b * 256 + t;                  // n may exceed NN-1 (harmless)
        int cc = min((e - pstart[t]) >> 3, 16);
        int s8 = base8 + (pstart[t] >> 3);
        meta[n] = (s8 << 5) | cc;
    }
    __syncthreads();
#pragma unroll
    for (int k = 0; k < 9; ++k) {
        if (k < nr) {
            int pos = atomicAdd(&rcur[rl[k]], 1);
            if (pos < SCAP) sorted[pos] = make_int2(rec[k].x & 0x1FFFF, rec[k].y);
        }
    }
    __syncthreads();
    int tp = pscan[255];
    int gb = base8 * 8;
    for (int i = t; i < tp; i += 512) {
        int gi = gb + i;
        if (gi < GCAP) gsorted[gi] = sorted[i];   // linear, fully coalesced
    }
}

// ===== K3: R0-style staged gather + MFMA transform + rownorm =====
// Per wave: 16 nodes. Each row's <=128 records staged global->LDS ebuf
// (coalesced, same-wave dep -> NO barriers anywhere), gathered from LDS.
// 13.3 KB LDS + VGPR<=64 -> 8 blocks/CU = 32 waves (100% occupancy cap).
__global__ __launch_bounds__(256, 8) void pull_mfma_kernel(
    const float* __restrict__ x, const int* __restrict__ meta,
    const int2* __restrict__ gsorted,
    const unsigned short* __restrict__ wb0, const unsigned short* __restrict__ wb1,
    const float* __restrict__ b0, const float* __restrict__ s0, const float* __restrict__ o0,
    const float* __restrict__ b1, const float* __restrict__ s1, const float* __restrict__ o1,
    float* __restrict__ out)
{
    __shared__ int2 ebuf[4][128];            // 4096 B (per-wave record stage)
    __shared__ unsigned aggt[4][16][36];     // 9216 B (16x64 bf16 per wave)

    int t = threadIdx.x, lane = t & 63, wv = t >> 6;
    int sub = lane & 15, q = lane >> 4;
    int nb0 = blockIdx.x * 64 + wv * 16;
    if (nb0 >= NN) return;                   // whole-wave tails; no barriers below

    // ---- phase 1: per row, stage records to LDS then gather-aggregate ----
    for (int rr = 0; rr < 16; ++rr) {
        int mt = meta[nb0 + rr];
        int cc = mt & 31;
        const int2* rp = gsorted + ((size_t)(mt >> 5) << 3);
        int plen = cc * 8;                   // <= 128
        if (lane < plen) ebuf[wv][lane] = rp[lane];
        if (64 + lane < plen) ebuf[wv][64 + lane] = rp[64 + lane];
        // same-wave global->LDS->read dependency: compiler inserts waits

        float4 acc = make_float4(0.f, 0.f, 0.f, 0.f);
        int ch = 0;
        for (; ch + 2 <= cc; ch += 2) {
            int2 r0 = ebuf[wv][ch * 8 + q];
            int2 r1 = ebuf[wv][ch * 8 + 4 + q];
            int2 r2 = ebuf[wv][ch * 8 + 8 + q];
            int2 r3 = ebuf[wv][ch * 8 + 12 + q];
            float4 f0 = *(const float4*)(x + (size_t)r0.x * DD + sub * 4);
            float4 f1 = *(const float4*)(x + (size_t)r1.x * DD + sub * 4);
            float4 f2 = *(const float4*)(x + (size_t)r2.x * DD + sub * 4);
            float4 f3 = *(const float4*)(x + (size_t)r3.x * DD + sub * 4);
            float v0 = __int_as_float(r0.y), v1 = __int_as_float(r1.y);
            float v2 = __int_as_float(r2.y), v3 = __int_as_float(r3.y);
            acc.x = fmaf(v0, f0.x, acc.x); acc.y = fmaf(v0, f0.y, acc.y);
            acc.z = fmaf(v0, f0.z, acc.z); acc.w = fmaf(v0, f0.w, acc.w);
            acc.x = fmaf(v1, f1.x, acc.x); acc.y = fmaf(v1, f1.y, acc.y);
            acc.z = fmaf(v1, f1.z, acc.z); acc.w = fmaf(v1, f1.w, acc.w);
            acc.x = fmaf(v2, f2.x, acc.x); acc.y = fmaf(v2, f2.y, acc.y);
            acc.z = fmaf(v2, f2.z, acc.z); acc.w = fmaf(v2, f2.w, acc.w);
            acc.x = fmaf(v3, f3.x, acc.x); acc.y = fmaf(v3, f3.y, acc.y);
            acc.z = fmaf(v3, f3.z, acc.z); acc.w = fmaf(v3, f3.w, acc.w);
        }
        if (ch < cc) {
            int2 r0 = ebuf[wv][ch * 8 + q];
            int2 r1 = ebuf[wv][ch * 8 + 4 + q];
            float4 f0 = *(const float4*)(x + (size_t)r0.x * DD + sub * 4);
            float4 f1 = *(const float4*)(x + (size_t)r1.x * DD + sub * 4);
            float v0 = __int_as_float(r0.y), v1 = __int_as_float(r1.y);
            acc.x = fmaf(v0, f0.x, acc.x); acc.y = fmaf(v0, f0.y, acc.y);
            acc.z = fmaf(v0, f0.z, acc.z); acc.w = fmaf(v0, f0.w, acc.w);
            acc.x = fmaf(v1, f1.x, acc.x); acc.y = fmaf(v1, f1.y, acc.y);
            acc.z = fmaf(v1, f1.z, acc.z); acc.w = fmaf(v1, f1.w, acc.w);
        }
        acc.x += __shfl_xor(acc.x, 16, 64); acc.y += __shfl_xor(acc.y, 16, 64);
        acc.z += __shfl_xor(acc.z, 16, 64); acc.w += __shfl_xor(acc.w, 16, 64);
        acc.x += __shfl_xor(acc.x, 32, 64); acc.y += __shfl_xor(acc.y, 32, 64);
        acc.z += __shfl_xor(acc.z, 32, 64); acc.w += __shfl_xor(acc.w, 32, 64);
        if (q == 0) {
            uint2 pk;
            pk.x = (unsigned)f2bfu(acc.x) | ((unsigned)f2bfu(acc.y) << 16);
            pk.y = (unsigned)f2bfu(acc.z) | ((unsigned)f2bfu(acc.w) << 16);
            *(uint2*)&aggt[wv][rr][sub * 2] = pk;
        }
    }
    // per-wave aggt tile: DS pipe in-order per wave -> no barrier needed

    // ---- phase 2: two-hop MFMA transform + rownorm for this wave's 16 nodes ----
    v8s ax[2], aa[2];
#pragma unroll
    for (int ks = 0; ks < 2; ++ks) {
        const float* px = x + (size_t)(nb0 + sub) * DD + ks * 32 + q * 8;
        float4 a0 = *(const float4*)px, a1 = *(const float4*)(px + 4);
        v8s w;
        w[0] = (short)f2bfu(a0.x); w[1] = (short)f2bfu(a0.y);
        w[2] = (short)f2bfu(a0.z); w[3] = (short)f2bfu(a0.w);
        w[4] = (short)f2bfu(a1.x); w[5] = (short)f2bfu(a1.y);
        w[6] = (short)f2bfu(a1.z); w[7] = (short)f2bfu(a1.w);
        ax[ks] = w;
        aa[ks] = *(const v8s*)&aggt[wv][sub][ks * 16 + q * 4];
    }

    float h0v[4][4], h1v[4][4];
    float sr0[4] = {0,0,0,0}, sq0[4] = {0,0,0,0};
    float sr1[4] = {0,0,0,0}, sq1[4] = {0,0,0,0};
#pragma unroll
    for (int dt = 0; dt < 4; ++dt) {
        int nidx = dt * 16 + sub;
        float bi0 = b0[nidx], bi1 = b1[nidx];
        v8s w00 = *(const v8s*)(wb0 + nidx * 64 + q * 8);
        v8s w01 = *(const v8s*)(wb0 + nidx * 64 + 32 + q * 8);
        v8s w10 = *(const v8s*)(wb1 + nidx * 64 + q * 8);
        v8s w11 = *(const v8s*)(wb1 + nidx * 64 + 32 + q * 8);
        v4f c0 = (v4f){bi0, bi0, bi0, bi0};
        v4f c1 = (v4f){bi1, bi1, bi1, bi1};
        c0 = __builtin_amdgcn_mfma_f32_16x16x32_bf16(ax[0], w00, c0, 0, 0, 0);
        c0 = __builtin_amdgcn_mfma_f32_16x16x32_bf16(ax[1], w01, c0, 0, 0, 0);
        c1 = __builtin_amdgcn_mfma_f32_16x16x32_bf16(aa[0], w10, c1, 0, 0, 0);
        c1 = __builtin_amdgcn_mfma_f32_16x16x32_bf16(aa[1], w11, c1, 0, 0, 0);
#pragma unroll
        for (int r = 0; r < 4; ++r) {
            float h = fmaxf(c0[r], 0.f); h0v[dt][r] = h; sr0[r] += h; sq0[r] += h * h;
            float g = fmaxf(c1[r], 0.f); h1v[dt][r] = g; sr1[r] += g; sq1[r] += g * g;
        }
    }
#pragma unroll
    for (int off = 1; off < 16; off <<= 1) {
#pragma unroll
        for (int r = 0; r < 4; ++r) {
            sr0[r] += __shfl_xor(sr0[r], off, 64);
            sq0[r] += __shfl_xor(sq0[r], off, 64);
            sr1[r] += __shfl_xor(sr1[r], off, 64);
            sq1[r] += __shfl_xor(sq1[r], off, 64);
        }
    }

    float scl0[4], scl1[4], ofs0[4], ofs1[4];
#pragma unroll
    for (int dt = 0; dt < 4; ++dt) {
        int nidx = dt * 16 + sub;
        scl0[dt] = s0[nidx]; scl1[dt] = s1[nidx];
        ofs0[dt] = o0[nidx]; ofs1[dt] = o1[nidx];
    }

    const float inv = 1.0f / 64.0f;
#pragma unroll
    for (int r = 0; r < 4; ++r) {
        float m0 = sr0[r] * inv;
        float v0 = fmaxf(sq0[r] * inv - m0 * m0, 0.f) + 1e-9f;
        float m1 = sr1[r] * inv;
        float v1 = fmaxf(sq1[r] * inv - m1 * m1, 0.f) + 1e-9f;
        float rs0 = rsqrtf(v0), rs1 = rsqrtf(v1);
        int node = nb0 + q * 4 + r;
#pragma unroll
        for (int dt = 0; dt < 4; ++dt) {
            float rv = (h0v[dt][r] - m0) * scl0[dt] * rs0 + ofs0[dt]
                     + (h1v[dt][r] - m1) * scl1[dt] * rs1 + ofs1[dt];
            out[(size_t)node * DD + dt * 16 + sub] = rv;   // 64B-coalesced per quad
        }
    }
}

extern "C" void kernel_launch(void* const* d_in, const int* in_sizes, int n_in,
                              void* d_out, int out_size, void* d_ws, size_t ws_size,
                              hipStream_t stream) {
    const float* x  = (const float*)d_in[0];
    const float* ev = (const float*)d_in[1];
    const float* W0 = (const float*)d_in[2];
    const float* b0 = (const float*)d_in[3];
    const float* s0 = (const float*)d_in[4];
    const float* o0 = (const float*)d_in[5];
    const float* W1 = (const float*)d_in[6];
    const float* b1 = (const float*)d_in[7];
    const float* s1 = (const float*)d_in[8];
    const float* o1 = (const float*)d_in[9];
    const int* row = (const int*)d_in[10];
    const int* col = (const int*)d_in[11];

    // ws byte layout (64B-aligned):
    //   gbcur:   0          (1564 B, pad 1600)
    //   gtail:   1600       (4 B, pad to 1664)
    //   wb0:     1664       (8192 B)
    //   wb1:     9856       (8192 B, end 18048, pad 18176)
    //   meta:    18176      (391*256*4 = 400384 B, end 418560, pad 418816)
    //   bslab:   418816     (391*4608*8 = 14,413,824 B, end 14,832,640)
    //   gsorted: 14,832,640 ((2,400,000+256)*8 = 19,202,048 B, end ~34.0 MB)
    char* wsb = (char*)d_ws;
    int*  gbcur = (int*)wsb;
    int*  gtail = (int*)(wsb + 1600);
    unsigned short* wb0 = (unsigned short*)(wsb + 1664);
    unsigned short* wb1 = (unsigned short*)(wsb + 9856);
    int*  meta  = (int*)(wsb + 18176);
    int2* bslab = (int2*)(wsb + 418816);
    int2* gsorted = (int2*)(wsb + 14832640);

    init_kernel<<<16, 256, 0, stream>>>(W0, W1, gbcur, gtail, wb0, wb1);
    bucket_scatter_kernel<<<NBK1, 512, 0, stream>>>(row, col, ev, gbcur, bslab);
    row_sort_kernel<<<NB, 512, 0, stream>>>(gbcur, bslab, gtail, gsorted, meta);
    pull_mfma_kernel<<<NK3, 256, 0, stream>>>(
        x, meta, gsorted, wb0, wb1, b0, s0, o0, b1, s1, o1, (float*)d_out);
}